// Round 7
// baseline (155.074 us; speedup 1.0000x reference)
//
#include <hip/hip_runtime.h>

// Selective scan as a PARALLEL (Blelloch-style) scan over t.
// x:(B,d,L) dA/dB:(B,d,L,n) C:(B,n,L) D:(d,) -> y:(B,d,L); B=64 d=384 L=197 n=16.
//
// h_t = a_t h_{t-1} + b_t is affine => associative compose (a2,b2)o(a1,b1) =
// (a1*a2, a2*b1+b2). Each 16-lane DPP row owns one (b,d) chain. A 16-step
// chunk: lane (p4,q) holds t = c*16+p4*4+j (j=0..3 regs), n = q*4+e (float4).
// Scan = 3 in-lane composes (over j) + 2 DPP row_shr steps (over p4) + carry.
// Per chunk per wave: 13 VMEM (dwordx4) + 8 DS ops -- ~8x fewer DS and 4x
// fewer VMEM instrs than the per-step-serial designs (R1-R5, all ~150us).
//
// R7 fix: update_dpp ctrl must be a compile-time constant -> template param.

#define B_   64
#define DIN  384
#define L_   197
#define N_   16
#define CSTR 20          // padded LDS stride for Cs (2-way max on b128 reads)
#define NCH  12          // full 16-step chunks (t=0..191); tail t=192..196

template<int CTRL>
__device__ __forceinline__ float dppmov(float src, float oldv) {
    return __int_as_float(__builtin_amdgcn_update_dpp(
        __float_as_int(oldv), __float_as_int(src), CTRL, 0xF, 0xF, false));
}
__device__ __forceinline__ float qsum(float p) {   // sum over 4-lane quad (VALU DPP)
    p += __int_as_float(__builtin_amdgcn_update_dpp(0, __float_as_int(p), 0xB1, 0xF, 0xF, true));
    p += __int_as_float(__builtin_amdgcn_update_dpp(0, __float_as_int(p), 0x4E, 0xF, 0xF, true));
    return p;
}
__device__ __forceinline__ float bcast12q(float v) {
    // lane <- lane ((l & 0x13) | 0x0C): row's lane 12+q  (BitMode 0x193)
    return __int_as_float(__builtin_amdgcn_ds_swizzle(__float_as_int(v), 0x193));
}

__global__ __launch_bounds__(256, 2)
void ssm_pscan(const float* __restrict__ x, const float* __restrict__ dA,
               const float* __restrict__ dB, const float* __restrict__ C,
               const float* __restrict__ D, float* __restrict__ y)
{
    __shared__ __align__(16) float Cs[L_ * CSTR];   // Cs[t*20+n] = C[b,n,t]

    const int tid = threadIdx.x;
    const int b   = blockIdx.y;

    const float* Cg = C + (size_t)b * (N_ * L_);
    for (int i = tid; i < N_ * L_; i += 256) {
        const int n = i / L_;
        const int t = i - n * L_;
        Cs[t * CSTR + n] = Cg[i];
    }
    __syncthreads();

    const int lane = tid & 63;
    const int wav  = tid >> 6;
    const int row  = lane >> 4;        // chain within wave (DPP row = 16 lanes)
    const int p    = lane & 15;
    const int p4   = p >> 2;           // t-quad
    const int q    = p & 3;            // n-quad

    const int d   = blockIdx.x * 16 + wav * 4 + row;
    const size_t bd = (size_t)b * DIN + d;

    const float* Arow = dA + bd * (size_t)(L_ * N_);
    const float* Brow = dB + bd * (size_t)(L_ * N_);
    const float* Xrow = x  + bd * L_;
    float*       Yrow = y  + bd * L_;
    const float  Dd   = D[d];
    const int laneAB  = p4 * 64 + q * 4;   // float offset within chunk
    const float* CsQ  = Cs + q * 4;

    float hcx = 0.f, hcy = 0.f, hcz = 0.f, hcw = 0.f;   // carry h[n=q*4+e]

    float4 PA0,PA1,PA2,PA3, PB0,PB1,PB2,PB3;
    float4 QA0,QA1,QA2,QA3, QB0,QB1,QB2,QB3;
    float  Px0,Px1,Px2,Px3, Qx0,Qx1,Qx2,Qx3;

#define LOADC(Pfx, c) do { \
    const float* _a = Arow + (c)*256 + laneAB; \
    const float* _g = Brow + (c)*256 + laneAB; \
    Pfx##A0 = *(const float4*)(_a +  0); Pfx##A1 = *(const float4*)(_a + 16); \
    Pfx##A2 = *(const float4*)(_a + 32); Pfx##A3 = *(const float4*)(_a + 48); \
    Pfx##B0 = *(const float4*)(_g +  0); Pfx##B1 = *(const float4*)(_g + 16); \
    Pfx##B2 = *(const float4*)(_g + 32); Pfx##B3 = *(const float4*)(_g + 48); \
    const float* _x = Xrow + (c)*16 + p4*4; \
    Pfx##x0 = _x[0]; Pfx##x1 = _x[1]; Pfx##x2 = _x[2]; Pfx##x3 = _x[3]; \
} while (0)

    // tail (t=192..196): clamp addresses into the row; lanes past t=196 hold
    // duplicate (finite) data, masked at store; only p4=0 (t=192..195) and
    // p4=1,j=0 (t=196) are stored.
#define LOADT(Pfx) do { \
    const int _tb = 192 + p4*4; \
    const int _t0 = _tb   > 196 ? 196 : _tb; \
    const int _t1 = _tb+1 > 196 ? 196 : _tb+1; \
    const int _t2 = _tb+2 > 196 ? 196 : _tb+2; \
    const int _t3 = _tb+3 > 196 ? 196 : _tb+3; \
    Pfx##A0 = *(const float4*)(Arow + _t0*16 + q*4); \
    Pfx##A1 = *(const float4*)(Arow + _t1*16 + q*4); \
    Pfx##A2 = *(const float4*)(Arow + _t2*16 + q*4); \
    Pfx##A3 = *(const float4*)(Arow + _t3*16 + q*4); \
    Pfx##B0 = *(const float4*)(Brow + _t0*16 + q*4); \
    Pfx##B1 = *(const float4*)(Brow + _t1*16 + q*4); \
    Pfx##B2 = *(const float4*)(Brow + _t2*16 + q*4); \
    Pfx##B3 = *(const float4*)(Brow + _t3*16 + q*4); \
    Pfx##x0 = Xrow[_t0]; Pfx##x1 = Xrow[_t1]; \
    Pfx##x2 = Xrow[_t2]; Pfx##x3 = Xrow[_t3]; \
} while (0)

    // per-component scan: bx, in-lane prefix (j), cross-quad DPP prefix,
    // exclusive shift, carry apply; h overwrites B.
#define SCANE(Pfx, E) do { \
    Pfx##B0.E *= Pfx##x0; Pfx##B1.E *= Pfx##x1; \
    Pfx##B2.E *= Pfx##x2; Pfx##B3.E *= Pfx##x3; \
    Pfx##B1.E = fmaf(Pfx##A1.E, Pfx##B0.E, Pfx##B1.E); Pfx##A1.E *= Pfx##A0.E; \
    Pfx##B2.E = fmaf(Pfx##A2.E, Pfx##B1.E, Pfx##B2.E); Pfx##A2.E *= Pfx##A1.E; \
    Pfx##B3.E = fmaf(Pfx##A3.E, Pfx##B2.E, Pfx##B3.E); Pfx##A3.E *= Pfx##A2.E; \
    float _ta = Pfx##A3.E, _tv = Pfx##B3.E; \
    { float _pa = dppmov<0x114>(_ta, 1.0f), _pb = dppmov<0x114>(_tv, 0.0f); \
      _tv = fmaf(_ta, _pb, _tv); _ta *= _pa; } \
    { float _pa = dppmov<0x118>(_ta, 1.0f), _pb = dppmov<0x118>(_tv, 0.0f); \
      _tv = fmaf(_ta, _pb, _tv); _ta *= _pa; } \
    const float _Ea = dppmov<0x114>(_ta, 1.0f); \
    const float _Eb = dppmov<0x114>(_tv, 0.0f); \
    const float _s  = fmaf(_Ea, hc##E, _Eb); \
    Pfx##B0.E = fmaf(Pfx##A0.E, _s, Pfx##B0.E); \
    Pfx##B1.E = fmaf(Pfx##A1.E, _s, Pfx##B1.E); \
    Pfx##B2.E = fmaf(Pfx##A2.E, _s, Pfx##B2.E); \
    Pfx##B3.E = fmaf(Pfx##A3.E, _s, Pfx##B3.E); \
} while (0)

#define YJ(Pfx, j, tcj, yf) do { \
    const float4 _c4 = *(const float4*)(CsQ + (tcj)*CSTR); \
    float _yp = fmaf(Pfx##B##j.x, _c4.x, fmaf(Pfx##B##j.y, _c4.y, \
                 fmaf(Pfx##B##j.z, _c4.z, Pfx##B##j.w * _c4.w))); \
    _yp = qsum(_yp); \
    yf = fmaf(Pfx##x##j, Dd, _yp); \
} while (0)

#define COMPUTE(Pfx, c, TAIL) do { \
    SCANE(Pfx, x); SCANE(Pfx, y); SCANE(Pfx, z); SCANE(Pfx, w); \
    const int _t0s = (TAIL) ? (192 + p4*4) : ((c)*16 + p4*4); \
    int _c0 = _t0s, _c1 = _t0s+1, _c2 = _t0s+2, _c3 = _t0s+3; \
    if (TAIL) { _c0 = _c0>196?196:_c0; _c1 = _c1>196?196:_c1; \
                _c2 = _c2>196?196:_c2; _c3 = _c3>196?196:_c3; } \
    float _yf0,_yf1,_yf2,_yf3; \
    YJ(Pfx, 0, _c0, _yf0); YJ(Pfx, 1, _c1, _yf1); \
    YJ(Pfx, 2, _c2, _yf2); YJ(Pfx, 3, _c3, _yf3); \
    hcx = bcast12q(Pfx##B3.x); hcy = bcast12q(Pfx##B3.y); \
    hcz = bcast12q(Pfx##B3.z); hcw = bcast12q(Pfx##B3.w); \
    const float _ys = (q==0) ? _yf0 : (q==1) ? _yf1 : (q==2) ? _yf2 : _yf3; \
    if (!(TAIL) || p4 == 0 || (p4 == 1 && q == 0)) Yrow[_t0s + q] = _ys; \
} while (0)

    LOADC(P, 0);
#pragma unroll 1
    for (int c = 0; c < NCH; c += 2) {
        LOADC(Q, c + 1);
        __builtin_amdgcn_sched_barrier(0);
        COMPUTE(P, c, 0);
        if (c + 2 < NCH) { LOADC(P, c + 2); } else { LOADT(P); }
        __builtin_amdgcn_sched_barrier(0);
        COMPUTE(Q, c + 1, 0);
    }
    COMPUTE(P, 0, 1);   // tail t=192..196

#undef COMPUTE
#undef YJ
#undef SCANE
#undef LOADT
#undef LOADC
}

extern "C" void kernel_launch(void* const* d_in, const int* in_sizes, int n_in,
                              void* d_out, int out_size, void* d_ws, size_t ws_size,
                              hipStream_t stream) {
    const float* x  = (const float*)d_in[0];
    const float* dA = (const float*)d_in[1];
    const float* dB = (const float*)d_in[2];
    const float* C  = (const float*)d_in[3];
    const float* D  = (const float*)d_in[4];
    float* yo = (float*)d_out;

    dim3 grid(DIN / 16, B_);   // (24, 64) = 1536 blocks, 16 chains/block
    dim3 block(256);           // 4 waves, 4 chains/wave
    ssm_pscan<<<grid, block, 0, stream>>>(x, dA, dB, C, D, yo);
}

// Round 8
// 142.532 us; speedup vs baseline: 1.0880x; 1.0880x over previous
//
#include <hip/hip_runtime.h>

// Selective scan, fp32.  x:(B,d,L) dA/dB:(B,d,L,n) C:(B,n,L) D:(d,) -> y:(B,d,L)
// B=64 d=384 L=197 n=16.
//
// Round-8 probe: MAXIMUM DRAM burst granularity. Each DMA op reads 1KB fully
// contiguous from ONE chain (16 t x 16 n floats) via global_load_lds(16).
// Wave-private double-buffered LDS tiles, counted s_waitcnt vmcnt(10) (one
// 9-op tile always in flight), zero barriers in the main loop. Compute is
// R5-style serial recurrence (lane = state n, 16 lanes per chain) reading
// from LDS; 16-lane reduction = 4 DPP adds (xor1, xor2, half-mirror, mirror)
// on the VALU pipe -- zero DS ops. Discriminates "read-service wall at
// ~4.5 TB/s" vs "DRAM row-buffer thrash from fine-grained streams".

#define B_   64
#define DIN  384
#define L_   197
#define N_   16
#define BUFW 2176            // floats/buf/wave: A 4x264 | B 4x264 | x 64
#define WAVEW (2*BUFW)       // double buffer
#define CS_OFF (2*WAVEW)     // 8704: Cs after the 2 waves' buffers
#define LDSW (CS_OFF + L_*N_)  // 11856 floats = 47424 B

typedef unsigned int u32as1 __attribute__((address_space(1)));
typedef unsigned int u32as3 __attribute__((address_space(3)));

__device__ __forceinline__ void gll16(const float* g, float* l) {
    __builtin_amdgcn_global_load_lds((const u32as1*)g, (u32as3*)l, 16, 0, 0);
}
__device__ __forceinline__ void gll4(const float* g, float* l) {
    __builtin_amdgcn_global_load_lds((const u32as1*)g, (u32as3*)l, 4, 0, 0);
}

template<int CTRL>
__device__ __forceinline__ float dppadd(float p) {
    return p + __int_as_float(__builtin_amdgcn_update_dpp(
        0, __float_as_int(p), CTRL, 0xF, 0xF, true));
}
// sum over 16 lanes, result in all 16 (quads become uniform stage by stage)
__device__ __forceinline__ float sum16(float p) {
    p = dppadd<0xB1>(p);    // quad_perm [1,0,3,2]  : xor 1
    p = dppadd<0x4E>(p);    // quad_perm [2,3,0,1]  : xor 2
    p = dppadd<0x141>(p);   // row_half_mirror      : quad exchange
    p = dppadd<0x140>(p);   // row_mirror           : 8-half exchange
    return p;
}

__global__ __launch_bounds__(128)
void ssm_burst(const float* __restrict__ x, const float* __restrict__ dA,
               const float* __restrict__ dB, const float* __restrict__ C,
               const float* __restrict__ D, float* __restrict__ y)
{
    __shared__ __align__(16) float lds[LDSW];

    const int tid = threadIdx.x;
    const int b   = blockIdx.y;
    const int d0  = blockIdx.x * 8;

    // stage Cs transposed once per block: Cs[t*16+n] = C[b,n,t]
    const float* Cg = C + (size_t)b * (N_ * L_);
    for (int i = tid; i < N_ * L_; i += 128) {
        const int n = i / L_;
        const int t = i - n * L_;
        lds[CS_OFF + t * N_ + n] = Cg[i];
    }
    __syncthreads();   // only barrier in the kernel

    const int wav  = tid >> 6;
    const int lane = tid & 63;
    const int g    = lane >> 4;    // chain within wave (4 chains/wave)
    const int n    = lane & 15;    // state index

    const int bd0 = b * DIN + d0 + wav * 4;
    const float* Arow = dA + (size_t)bd0 * (L_ * N_);  // chain c at +c*L*N
    const float* Brow = dB + (size_t)bd0 * (L_ * N_);
    const float* Xrow = x  + (size_t)bd0 * L_;
    float*       Yrow = y  + (size_t)(bd0 + g) * L_;
    const float  Dd   = D[d0 + wav * 4 + g];

    float* wl = lds + wav * WAVEW;   // wave-private LDS region
    const int lane4 = lane * 4;      // 16B per lane within a 1KB chain burst

    // one tile = 16 steps for 4 chains: 8x gll16 (A,B) + 1x gll4 (x) = 9 ops
#define STAGE(buf, t0) do { \
    float* _d = wl + (buf) * BUFW; \
    gll16(Arow + 0*(L_*N_) + (t0)*16 + lane4, _d + 0*264); \
    gll16(Arow + 1*(L_*N_) + (t0)*16 + lane4, _d + 1*264); \
    gll16(Arow + 2*(L_*N_) + (t0)*16 + lane4, _d + 2*264); \
    gll16(Arow + 3*(L_*N_) + (t0)*16 + lane4, _d + 3*264); \
    gll16(Brow + 0*(L_*N_) + (t0)*16 + lane4, _d + 1056 + 0*264); \
    gll16(Brow + 1*(L_*N_) + (t0)*16 + lane4, _d + 1056 + 1*264); \
    gll16(Brow + 2*(L_*N_) + (t0)*16 + lane4, _d + 1056 + 2*264); \
    gll16(Brow + 3*(L_*N_) + (t0)*16 + lane4, _d + 1056 + 3*264); \
    gll4(Xrow + g * L_ + (t0) + n, _d + 2112); \
} while (0)

#define STEP(j, xv, tg0, J0) do { \
    if ((j) >= (J0)) { \
        const float _a = _ab[g*264 + (j)*16 + n]; \
        const float _g = _ab[1056 + g*264 + (j)*16 + n]; \
        h = fmaf(_a, h, _g * (xv)); \
        float _p = h * lds[CS_OFF + ((tg0)+(j))*16 + n]; \
        _p = sum16(_p); \
        const float _yt = fmaf((xv), Dd, _p); \
        _ys = (n == (j)) ? _yt : _ys; \
    } \
} while (0)

#define TILEBODY(buf, tg0, J0) do { \
    const float* _ab = wl + (buf) * BUFW; \
    float _ys = 0.f; \
    const float4 _x0 = *(const float4*)(_ab + 2112 + g*16 + 0); \
    const float4 _x1 = *(const float4*)(_ab + 2112 + g*16 + 4); \
    const float4 _x2 = *(const float4*)(_ab + 2112 + g*16 + 8); \
    const float4 _x3 = *(const float4*)(_ab + 2112 + g*16 + 12); \
    STEP( 0, _x0.x, tg0, J0); STEP( 1, _x0.y, tg0, J0); \
    STEP( 2, _x0.z, tg0, J0); STEP( 3, _x0.w, tg0, J0); \
    STEP( 4, _x1.x, tg0, J0); STEP( 5, _x1.y, tg0, J0); \
    STEP( 6, _x1.z, tg0, J0); STEP( 7, _x1.w, tg0, J0); \
    STEP( 8, _x2.x, tg0, J0); STEP( 9, _x2.y, tg0, J0); \
    STEP(10, _x2.z, tg0, J0); STEP(11, _x2.w, tg0, J0); \
    STEP(12, _x3.x, tg0, J0); STEP(13, _x3.y, tg0, J0); \
    STEP(14, _x3.z, tg0, J0); STEP(15, _x3.w, tg0, J0); \
    if ((J0) == 0) Yrow[(tg0) + n] = _ys; \
    else if (n >= (J0)) Yrow[(tg0) + n] = _ys; \
} while (0)

    float h = 0.f;

    // 12 full tiles (t0 = 0..176) + tail staged at 181 (compute j=11..15).
    STAGE(0, 0);
    STAGE(1, 16);
    asm volatile("s_waitcnt vmcnt(9)" ::: "memory");   // tile0 resident
    TILEBODY(0, 0, 0);

#pragma unroll 1
    for (int k = 1; k <= 11; ++k) {
        const int tn = (k < 11) ? (k + 1) * 16 : 181;  // tail window 181..196
        STAGE((k + 1) & 1, tn);
        // oldest 9 (tile k) drained; store(k-1) + 9 new stay in flight
        asm volatile("s_waitcnt vmcnt(10)" ::: "memory");
        TILEBODY(k & 1, k * 16, 0);
    }
    asm volatile("s_waitcnt vmcnt(0)" ::: "memory");
    TILEBODY(0, 181, 11);   // t = 192..196, h carried from t=191

#undef TILEBODY
#undef STEP
#undef STAGE
}

extern "C" void kernel_launch(void* const* d_in, const int* in_sizes, int n_in,
                              void* d_out, int out_size, void* d_ws, size_t ws_size,
                              hipStream_t stream) {
    const float* x  = (const float*)d_in[0];
    const float* dA = (const float*)d_in[1];
    const float* dB = (const float*)d_in[2];
    const float* C  = (const float*)d_in[3];
    const float* D  = (const float*)d_in[4];
    float* yo = (float*)d_out;

    dim3 grid(DIN / 8, B_);   // (48, 64) = 3072 blocks; 8 chains/block
    dim3 block(128);          // 2 waves; wave-private tiles, no loop barriers
    ssm_burst<<<grid, block, 0, stream>>>(x, dA, dB, C, D, yo);
}